// Round 10
// baseline (1273.010 us; speedup 1.0000x reference)
//
#include <hip/hip_runtime.h>
#include <math.h>

#define E 16
#define D 64
#define H 128
#define R 4            // n-rows per block
#define ROWS (R * E)   // 64 expert-rows per block
#define MW 16          // expert-rows per wave
#define SA 132         // bufA stride (floats): 16-row strided b128 reads -> 2-way (free)
#define GAP_TAU 2e-3f  // exact-recompute guard threshold (200x the mfma-emulation error)

typedef __attribute__((ext_vector_type(8))) short bf16x8;
typedef __attribute__((ext_vector_type(4))) float f32x4;

#define WS_NEED ((size_t)(8 * 8 * 3 * 64 * 8) * sizeof(unsigned short))  // 196608 B

// Split fp32 -> 3 bf16 slices by truncation (exact residuals).
__device__ __forceinline__ void split3_8(const float* v, bf16x8& s1, bf16x8& s2, bf16x8& s3) {
#pragma unroll
    for (int i = 0; i < 8; i++) {
        float x = v[i];
        unsigned u1 = __float_as_uint(x) & 0xffff0000u;
        float r1 = x - __uint_as_float(u1);
        unsigned u2 = __float_as_uint(r1) & 0xffff0000u;
        float r2 = r1 - __uint_as_float(u2);
        unsigned u3 = __float_as_uint(r2) & 0xffff0000u;
        s1[i] = (short)(u1 >> 16);
        s2[i] = (short)(u2 >> 16);
        s3[i] = (short)(u3 >> 16);
    }
}

// ---------------------------------------------------------------------------
// Prep: pack B = [Wabc ; Wd] (K=256 x N=128) as 3 bf16 slices in MFMA
// B-fragment order: idx = ((s*8 + t)*3 + slice)*512 + lane*8 shorts, where
// lane holds B[k = s*32 + (lane>>4)*8 + j][n = t*16 + (lane&15)], j=0..7.
// ---------------------------------------------------------------------------
__global__ void spec_pack(const float* __restrict__ specW1, unsigned short* __restrict__ bw) {
    int tid = blockIdx.x * blockDim.x + threadIdx.x;
    if (tid >= 4096) return;
    const int lane = tid & 63;
    const int t    = (tid >> 6) & 7;
    const int s    = tid >> 9;
    const int n    = t * 16 + (lane & 15);
    const int kb   = s * 32 + (lane >> 4) * 8;
    float w[8];
#pragma unroll
    for (int j = 0; j < 8; j++) {
        int k = kb + j;
        if (k < H) w[j] = specW1[k * H + n] + specW1[(H + k) * H + n] + specW1[(2 * H + k) * H + n];
        else       w[j] = specW1[(3 * H + (k - H)) * H + n];
    }
    bf16x8 s1, s2, s3;
    split3_8(w, s1, s2, s3);
    size_t base = ((size_t)(s * 8 + t) * 3) * 512 + (size_t)lane * 8;
    *(bf16x8*)(bw + base)        = s1;
    *(bf16x8*)(bw + base + 512)  = s2;
    *(bf16x8*)(bw + base + 1024) = s3;
}

// ---------------------------------------------------------------------------
// MFMA router. Encoder/stats/GEMV = R7-champion fp32 structure. Spec GEMM =
// bf16x3-split MFMA (6 products), M=16 expert-rows/wave, 8 N-tiles, 8 K-steps.
// Rows whose top-k boundary gap < GAP_TAU are recomputed exactly in fp32.
// ---------------------------------------------------------------------------
__global__ __launch_bounds__(256, 2)
void router_mfma(const float* __restrict__ tokens,
                 const float* __restrict__ encW1, const float* __restrict__ encB1,
                 const float* __restrict__ encW2, const float* __restrict__ encB2,
                 const float* __restrict__ specW1, const float* __restrict__ specB1,
                 const float* __restrict__ specW2,
                 const float* __restrict__ defW1, const float* __restrict__ defB1,
                 const float* __restrict__ defW2, const float* __restrict__ defB2,
                 const int* __restrict__ fiPtr, const int* __restrict__ tkPtr,
                 const unsigned short* __restrict__ bslices,
                 float* __restrict__ out, int N) {
    __shared__ float bufA[ROWS * SA];   // 33.8 KB: tokens (dense) -> encoded (stride SA)
    __shared__ float bufB[ROWS * H];    // 32 KB: h; after enc2: GEMV partial scratch
    __shared__ float s_full[R * H];
    __shared__ float s_glob[R * H];
    __shared__ float s_mabs[R * H];
    __shared__ float s_bias[R * H];
    __shared__ float s_logits[ROWS];
    __shared__ float s_dred[R];
    __shared__ int   s_flag[R];

    const int tid   = threadIdx.x;
    const int n0    = blockIdx.x * R;
    const int fi    = fiPtr[0];
    const int lane  = tid & 63;
    const int wq    = tid >> 6;        // wave == n-row
    const int mbase = wq * MW;
    const int hw    = lane >> 5;       // half-wave (encoder tiling)
    const int jl    = lane & 31;
    const int jw0   = jl * 4;
    const int mb2   = mbase + hw * 8;

    // ---- stage 1: tokens -> bufA (dense, 64 floats/row) ----
    {
        const size_t base  = (size_t)n0 * (E * D);
        const size_t total = (size_t)N * (E * D);
        float4* dst = (float4*)bufA;
#pragma unroll
        for (int it = 0; it < 4; it++) {
            int f = tid + it * 256;
            size_t off = base + (size_t)f * 4;
            float4 v = make_float4(0.f, 0.f, 0.f, 0.f);
            if (off + 3 < total) v = *(const float4*)(tokens + off);
            dst[f] = v;
        }
    }
    __syncthreads();

    // ---- stage 2: enc1 h = relu(tok @ W1 + b1), K=64; bufA(dense) -> bufB ----
    {
        float acc[8][4];
#pragma unroll
        for (int m = 0; m < 8; m++)
#pragma unroll
            for (int j = 0; j < 4; j++) acc[m][j] = 0.f;
#pragma unroll 2
        for (int k = 0; k < D; k += 4) {
            float4 w0 = *(const float4*)(encW1 + (k + 0) * H + jw0);
            float4 w1 = *(const float4*)(encW1 + (k + 1) * H + jw0);
            float4 w2 = *(const float4*)(encW1 + (k + 2) * H + jw0);
            float4 w3 = *(const float4*)(encW1 + (k + 3) * H + jw0);
#pragma unroll
            for (int m = 0; m < 8; m++) {
                float4 t = *(const float4*)(bufA + (mb2 + m) * D + k);
                acc[m][0] = fmaf(t.w, w3.x, fmaf(t.z, w2.x, fmaf(t.y, w1.x, fmaf(t.x, w0.x, acc[m][0]))));
                acc[m][1] = fmaf(t.w, w3.y, fmaf(t.z, w2.y, fmaf(t.y, w1.y, fmaf(t.x, w0.y, acc[m][1]))));
                acc[m][2] = fmaf(t.w, w3.z, fmaf(t.z, w2.z, fmaf(t.y, w1.z, fmaf(t.x, w0.z, acc[m][2]))));
                acc[m][3] = fmaf(t.w, w3.w, fmaf(t.z, w2.w, fmaf(t.y, w1.w, fmaf(t.x, w0.w, acc[m][3]))));
            }
        }
        float4 b = *(const float4*)(encB1 + jw0);
        __syncthreads();   // bufA token reads done before enc2 overwrites bufA later; cheap
#pragma unroll
        for (int m = 0; m < 8; m++) {
            float4 o;
            o.x = fmaxf(acc[m][0] + b.x, 0.f);
            o.y = fmaxf(acc[m][1] + b.y, 0.f);
            o.z = fmaxf(acc[m][2] + b.z, 0.f);
            o.w = fmaxf(acc[m][3] + b.w, 0.f);
            *(float4*)(bufB + (mb2 + m) * H + jw0) = o;
        }
    }
    __syncthreads();

    // ---- stage 3: enc2 encoded = relu(h @ W2 + b2), K=128; bufB -> bufA(SA) ----
    {
        float acc[8][4];
#pragma unroll
        for (int m = 0; m < 8; m++)
#pragma unroll
            for (int j = 0; j < 4; j++) acc[m][j] = 0.f;
#pragma unroll 2
        for (int k = 0; k < H; k += 4) {
            float4 w0 = *(const float4*)(encW2 + (k + 0) * H + jw0);
            float4 w1 = *(const float4*)(encW2 + (k + 1) * H + jw0);
            float4 w2 = *(const float4*)(encW2 + (k + 2) * H + jw0);
            float4 w3 = *(const float4*)(encW2 + (k + 3) * H + jw0);
#pragma unroll
            for (int m = 0; m < 8; m++) {
                float4 t = *(const float4*)(bufB + (mb2 + m) * H + k);
                acc[m][0] = fmaf(t.w, w3.x, fmaf(t.z, w2.x, fmaf(t.y, w1.x, fmaf(t.x, w0.x, acc[m][0]))));
                acc[m][1] = fmaf(t.w, w3.y, fmaf(t.z, w2.y, fmaf(t.y, w1.y, fmaf(t.x, w0.y, acc[m][1]))));
                acc[m][2] = fmaf(t.w, w3.z, fmaf(t.z, w2.z, fmaf(t.y, w1.z, fmaf(t.x, w0.z, acc[m][2]))));
                acc[m][3] = fmaf(t.w, w3.w, fmaf(t.z, w2.w, fmaf(t.y, w1.w, fmaf(t.x, w0.w, acc[m][3]))));
            }
        }
        float4 b = *(const float4*)(encB2 + jw0);
#pragma unroll
        for (int m = 0; m < 8; m++) {
            float4 o;
            o.x = fmaxf(acc[m][0] + b.x, 0.f);
            o.y = fmaxf(acc[m][1] + b.y, 0.f);
            o.z = fmaxf(acc[m][2] + b.z, 0.f);
            o.w = fmaxf(acc[m][3] + b.w, 0.f);
            *(float4*)(bufA + (mb2 + m) * SA + jw0) = o;
        }
    }
    __syncthreads();

    // ---- stage 4: stats: full, glob mean, mean|delta| ----
    {
        const int r4 = tid >> 6;
        const int cb = tid & 63;
#pragma unroll
        for (int half = 0; half < 2; half++) {
            const int c = cb + half * 64;
            const float* er = bufA + (r4 * E) * SA + c;
            float v[E];
#pragma unroll
            for (int e = 0; e < E; e++) v[e] = er[e * SA];
            float s = 0.f;
#pragma unroll
            for (int e = 0; e < E; e++) s += v[e];
            float fc = v[fi];
            float ma = 0.f;
#pragma unroll
            for (int e = 0; e < E; e++) ma += fabsf(v[e] - fc);
            s_full[r4 * H + c] = fc;
            s_glob[r4 * H + c] = s * (1.f / 16.f);
            s_mabs[r4 * H + c] = ma * (1.f / 16.f);
        }
    }
    __syncthreads();

    // ---- stage 5a: GEMV partials into dead bufB ----
    float* s_pB = bufB;
    float* s_pD = bufB + 2 * R * H;
    {
        const int jp = tid & 63;
        const int jj = jp * 2;
        const int kh = (tid >> 6) & 1;
        const int rg = tid >> 7;
        const int c0 = kh * 64;
        const float* __restrict__ Wb = specW1 + H * H;
        const float* __restrict__ Wc = specW1 + 2 * H * H;
        float accB[2][2] = {{0.f, 0.f}, {0.f, 0.f}};
        float accD[2][2] = {{0.f, 0.f}, {0.f, 0.f}};
        for (int cc = 0; cc < 64; cc++) {
            const int c = c0 + cc;
            float2 wb = *(const float2*)(Wb + c * H + jj);
            float2 wc = *(const float2*)(Wc + c * H + jj);
            float2 d0 = *(const float2*)(defW1 + c * H + jj);
            float2 d1 = *(const float2*)(defW1 + (H + c) * H + jj);
            float2 d2 = *(const float2*)(defW1 + (2 * H + c) * H + jj);
#pragma unroll
            for (int rl = 0; rl < 2; rl++) {
                const int r = rg * 2 + rl;
                float fv = s_full[r * H + c];
                float gv = s_glob[r * H + c];
                float mv = s_mabs[r * H + c];
                accB[rl][0] = fmaf(fv, wb.x, accB[rl][0]);
                accB[rl][1] = fmaf(fv, wb.y, accB[rl][1]);
                accB[rl][0] = fmaf(gv, wc.x, accB[rl][0]);
                accB[rl][1] = fmaf(gv, wc.y, accB[rl][1]);
                accD[rl][0] = fmaf(fv, d0.x, accD[rl][0]);
                accD[rl][1] = fmaf(fv, d0.y, accD[rl][1]);
                accD[rl][0] = fmaf(gv, d1.x, accD[rl][0]);
                accD[rl][1] = fmaf(gv, d1.y, accD[rl][1]);
                accD[rl][0] = fmaf(mv, d2.x, accD[rl][0]);
                accD[rl][1] = fmaf(mv, d2.y, accD[rl][1]);
            }
        }
#pragma unroll
        for (int rl = 0; rl < 2; rl++) {
            const int r = rg * 2 + rl;
            *(float2*)(s_pB + (kh * R + r) * H + jj) = make_float2(accB[rl][0], accB[rl][1]);
            *(float2*)(s_pD + (kh * R + r) * H + jj) = make_float2(accD[rl][0], accD[rl][1]);
        }
    }
    __syncthreads();

    // ---- stage 5b: finalize bias + defer logit ----
    {
        float dv = 0.f;
#pragma unroll
        for (int t = 0; t < 2; t++) {
            const int j = lane + t * 64;
            float pb = s_pB[wq * H + j] + s_pB[(R + wq) * H + j];
            s_bias[wq * H + j] = specB1[j] - pb;
            float pd = defB1[j] + s_pD[wq * H + j] + s_pD[(R + wq) * H + j];
            dv += fmaxf(pd, 0.f) * defW2[j];
        }
#pragma unroll
        for (int off = 32; off; off >>= 1) dv += __shfl_xor(dv, off, 64);
        if (lane == 0) s_dred[wq] = dv;
    }
    __syncthreads();

    // ---- stage 6: spec GEMM via bf16x3-split MFMA (6 products) ----
    {
        const int m    = lane & 15;
        const int quad = lane >> 4;
        const int row  = mbase + m;
        f32x4 acc[8];
#pragma unroll
        for (int t = 0; t < 8; t++)
#pragma unroll
            for (int g = 0; g < 4; g++) acc[t][g] = 0.f;
#pragma unroll 1
        for (int s = 0; s < 8; s++) {
            const int kb = s * 32 + quad * 8;
            float v[8];
            if (kb < H) {
                float4 a0 = *(const float4*)(bufA + row * SA + kb);
                float4 a1 = *(const float4*)(bufA + row * SA + kb + 4);
                v[0] = a0.x; v[1] = a0.y; v[2] = a0.z; v[3] = a0.w;
                v[4] = a1.x; v[5] = a1.y; v[6] = a1.z; v[7] = a1.w;
            } else {
                const int kc = kb - H;
                float4 a0 = *(const float4*)(bufA + row * SA + kc);
                float4 a1 = *(const float4*)(bufA + row * SA + kc + 4);
                float4 f0 = *(const float4*)(s_full + wq * H + kc);
                float4 f1 = *(const float4*)(s_full + wq * H + kc + 4);
                v[0] = fabsf(a0.x - f0.x); v[1] = fabsf(a0.y - f0.y);
                v[2] = fabsf(a0.z - f0.z); v[3] = fabsf(a0.w - f0.w);
                v[4] = fabsf(a1.x - f1.x); v[5] = fabsf(a1.y - f1.y);
                v[6] = fabsf(a1.z - f1.z); v[7] = fabsf(a1.w - f1.w);
            }
            bf16x8 x1, x2, x3;
            split3_8(v, x1, x2, x3);
#pragma unroll
            for (int t = 0; t < 8; t++) {
                const unsigned short* bp = bslices + ((size_t)(s * 8 + t) * 3) * 512 + (size_t)lane * 8;
                bf16x8 b1 = *(const bf16x8*)(bp);
                bf16x8 b2 = *(const bf16x8*)(bp + 512);
                bf16x8 b3 = *(const bf16x8*)(bp + 1024);
                acc[t] = __builtin_amdgcn_mfma_f32_16x16x32_bf16(x1, b1, acc[t], 0, 0, 0);
                acc[t] = __builtin_amdgcn_mfma_f32_16x16x32_bf16(x1, b2, acc[t], 0, 0, 0);
                acc[t] = __builtin_amdgcn_mfma_f32_16x16x32_bf16(x2, b1, acc[t], 0, 0, 0);
                acc[t] = __builtin_amdgcn_mfma_f32_16x16x32_bf16(x1, b3, acc[t], 0, 0, 0);
                acc[t] = __builtin_amdgcn_mfma_f32_16x16x32_bf16(x3, b1, acc[t], 0, 0, 0);
                acc[t] = __builtin_amdgcn_mfma_f32_16x16x32_bf16(x2, b2, acc[t], 0, 0, 0);
            }
        }
        // epilogue: C/D layout col=lane&15, row=quad*4+reg; reduce cols over 16 lanes
        float part[4] = {0.f, 0.f, 0.f, 0.f};
#pragma unroll
        for (int t = 0; t < 8; t++) {
            const int j = t * 16 + m;
            float bj = s_bias[wq * H + j];
            float wj = specW2[j];
#pragma unroll
            for (int g = 0; g < 4; g++)
                part[g] += fmaxf(acc[t][g] + bj, 0.f) * wj;
        }
#pragma unroll
        for (int off = 1; off < 16; off <<= 1)
#pragma unroll
            for (int g = 0; g < 4; g++) part[g] += __shfl_xor(part[g], off, 64);
        if (m == 0)
#pragma unroll
            for (int g = 0; g < 4; g++) s_logits[wq * E + quad * 4 + g] = part[g];
    }
    __syncthreads();

    // ---- stage 6b: boundary-gap guard ----
    if (tid < R) {
        int k = tkPtr[0];
        if (k < 1) k = 1;
        if (k > E - 1) k = E - 1;
        float lg[E];
#pragma unroll
        for (int e = 0; e < E; e++) lg[e] = s_logits[tid * E + e];
        unsigned chosen = 0u;
        for (int kk = 0; kk < k; kk++) {
            float bv = -INFINITY; int bi = 0;
            for (int e = 0; e < E; e++) {
                if (e == fi || ((chosen >> e) & 1u)) continue;
                if (lg[e] > bv) { bv = lg[e]; bi = e; }
            }
            chosen |= (1u << bi);
        }
        float cmin = INFINITY, umax = -INFINITY;
        for (int e = 0; e < E; e++) {
            if (e == fi) continue;
            if ((chosen >> e) & 1u) cmin = fminf(cmin, lg[e]);
            else                    umax = fmaxf(umax, lg[e]);
        }
        s_flag[tid] = (cmin - umax < GAP_TAU) ? 1 : 0;
    }
    __syncthreads();

    // ---- stage 6c: exact fp32 recompute for flagged rows (rare) ----
    for (int r = 0; r < R; r++) {
        if (s_flag[r]) {
            const int e  = tid >> 4;
            const int jb = (tid & 15) * 8;
            const float* er = bufA + (r * E + e) * SA;
            const float* fr = s_full + r * H;
            float a[8];
#pragma unroll
            for (int jj = 0; jj < 8; jj++) a[jj] = s_bias[r * H + jb + jj];
            for (int kk = 0; kk < H; kk++) {
                float ev = er[kk];
                float ad = fabsf(ev - fr[kk]);
                const float* p = specW1 + kk * H + jb;
                float4 w0a = *(const float4*)(p);
                float4 w0b = *(const float4*)(p + 4);
                float4 w1a = *(const float4*)(p + H * H);
                float4 w1b = *(const float4*)(p + H * H + 4);
                float4 w2a = *(const float4*)(p + 2 * H * H);
                float4 w2b = *(const float4*)(p + 2 * H * H + 4);
                float4 w3a = *(const float4*)(p + 3 * H * H);
                float4 w3b = *(const float4*)(p + 3 * H * H + 4);
                a[0] = fmaf(ad, w3a.x, fmaf(ev, w0a.x + w1a.x + w2a.x, a[0]));
                a[1] = fmaf(ad, w3a.y, fmaf(ev, w0a.y + w1a.y + w2a.y, a[1]));
                a[2] = fmaf(ad, w3a.z, fmaf(ev, w0a.z + w1a.z + w2a.z, a[2]));
                a[3] = fmaf(ad, w3a.w, fmaf(ev, w0a.w + w1a.w + w2a.w, a[3]));
                a[4] = fmaf(ad, w3b.x, fmaf(ev, w0b.x + w1b.x + w2b.x, a[4]));
                a[5] = fmaf(ad, w3b.y, fmaf(ev, w0b.y + w1b.y + w2b.y, a[5]));
                a[6] = fmaf(ad, w3b.z, fmaf(ev, w0b.z + w1b.z + w2b.z, a[6]));
                a[7] = fmaf(ad, w3b.w, fmaf(ev, w0b.w + w1b.w + w2b.w, a[7]));
            }
            float part = 0.f;
#pragma unroll
            for (int jj = 0; jj < 8; jj++)
                part += fmaxf(a[jj], 0.f) * specW2[jb + jj];
#pragma unroll
            for (int off = 1; off < 16; off <<= 1) part += __shfl_xor(part, off, 64);
            if ((tid & 15) == 0) s_logits[r * E + e] = part;
        }
    }
    __syncthreads();

    // ---- stage 8: finalize (R threads: one per n-row) ----
    if (tid < R && (n0 + tid) < N) {
        const int r = tid;
        const int n = n0 + r;
        float s = s_dred[r] + defB2[0];
        out[(size_t)N * E + n] = 1.f / (1.f + expf(-s));
        int k = tkPtr[0];
        if (k < 1) k = 1;
        if (k > E - 1) k = E - 1;
        unsigned chosen = 0u;
        for (int kk = 0; kk < k; kk++) {
            float bv = -INFINITY; int bi = 0;
            for (int e = 0; e < E; e++) {
                if (e == fi || ((chosen >> e) & 1u)) continue;
                float v = s_logits[r * E + e];
                if (v > bv) { bv = v; bi = e; }
            }
            chosen |= (1u << bi);
        }
        float mx = -INFINITY;
        for (int e = 0; e < E; e++)
            if ((chosen >> e) & 1u) { float v = s_logits[r * E + e]; if (v > mx) mx = v; }
        float ssum = 0.f;
        for (int e = 0; e < E; e++)
            if ((chosen >> e) & 1u) ssum += expf(s_logits[r * E + e] - mx);
        float inv = 1.f / ssum;
        for (int e = 0; e < E; e++) {
            float wv = 0.f;
            if ((chosen >> e) & 1u) wv = expf(s_logits[r * E + e] - mx) * inv;
            out[(size_t)n * E + e] = wv;
        }
    }
}

// ---------------------------------------------------------------------------
// Fallback: R7-champion all-fp32 kernel (no workspace needed).
// ---------------------------------------------------------------------------
__global__ __launch_bounds__(256, 2)
void router_fp32(const float* __restrict__ tokens,
                 const float* __restrict__ encW1, const float* __restrict__ encB1,
                 const float* __restrict__ encW2, const float* __restrict__ encB2,
                 const float* __restrict__ specW1, const float* __restrict__ specB1,
                 const float* __restrict__ specW2,
                 const float* __restrict__ defW1, const float* __restrict__ defB1,
                 const float* __restrict__ defW2, const float* __restrict__ defB2,
                 const int* __restrict__ fiPtr, const int* __restrict__ tkPtr,
                 float* __restrict__ out, int N) {
    __shared__ float bufA[ROWS * H];
    __shared__ float bufB[ROWS * H];
    __shared__ float s_full[R * H];
    __shared__ float s_glob[R * H];
    __shared__ float s_mabs[R * H];
    __shared__ float s_bias[R * H];
    __shared__ float s_logits[ROWS];
    __shared__ float s_dred[R];

    const int tid   = threadIdx.x;
    const int n0    = blockIdx.x * R;
    const int fi    = fiPtr[0];
    const int lane  = tid & 63;
    const int wq    = tid >> 6;
    const int mbase = wq * MW;
    const int hw    = lane >> 5;
    const int jl    = lane & 31;
    const int jw0   = jl * 4;
    const int mb2   = mbase + hw * 8;

    {
        const size_t base  = (size_t)n0 * (E * D);
        const size_t total = (size_t)N * (E * D);
        float4* dst = (float4*)bufA;
#pragma unroll
        for (int it = 0; it < 4; it++) {
            int f = tid + it * 256;
            size_t off = base + (size_t)f * 4;
            float4 v = make_float4(0.f, 0.f, 0.f, 0.f);
            if (off + 3 < total) v = *(const float4*)(tokens + off);
            dst[f] = v;
        }
    }
    __syncthreads();
    {
        float acc[8][4];
#pragma unroll
        for (int m = 0; m < 8; m++)
#pragma unroll
            for (int j = 0; j < 4; j++) acc[m][j] = 0.f;
#pragma unroll 2
        for (int k = 0; k < D; k += 4) {
            float4 w0 = *(const float4*)(encW1 + (k + 0) * H + jw0);
            float4 w1 = *(const float4*)(encW1 + (k + 1) * H + jw0);
            float4 w2 = *(const float4*)(encW1 + (k + 2) * H + jw0);
            float4 w3 = *(const float4*)(encW1 + (k + 3) * H + jw0);
#pragma unroll
            for (int m = 0; m < 8; m++) {
                float4 t = *(const float4*)(bufA + (mb2 + m) * D + k);
                acc[m][0] = fmaf(t.w, w3.x, fmaf(t.z, w2.x, fmaf(t.y, w1.x, fmaf(t.x, w0.x, acc[m][0]))));
                acc[m][1] = fmaf(t.w, w3.y, fmaf(t.z, w2.y, fmaf(t.y, w1.y, fmaf(t.x, w0.y, acc[m][1]))));
                acc[m][2] = fmaf(t.w, w3.z, fmaf(t.z, w2.z, fmaf(t.y, w1.z, fmaf(t.x, w0.z, acc[m][2]))));
                acc[m][3] = fmaf(t.w, w3.w, fmaf(t.z, w2.w, fmaf(t.y, w1.w, fmaf(t.x, w0.w, acc[m][3]))));
            }
        }
        float4 b = *(const float4*)(encB1 + jw0);
        __syncthreads();
#pragma unroll
        for (int m = 0; m < 8; m++) {
            float4 o;
            o.x = fmaxf(acc[m][0] + b.x, 0.f);
            o.y = fmaxf(acc[m][1] + b.y, 0.f);
            o.z = fmaxf(acc[m][2] + b.z, 0.f);
            o.w = fmaxf(acc[m][3] + b.w, 0.f);
            *(float4*)(bufB + (mb2 + m) * H + jw0) = o;
        }
    }
    __syncthreads();
    {
        float acc[8][4];
#pragma unroll
        for (int m = 0; m < 8; m++)
#pragma unroll
            for (int j = 0; j < 4; j++) acc[m][j] = 0.f;
#pragma unroll 2
        for (int k = 0; k < H; k += 4) {
            float4 w0 = *(const float4*)(encW2 + (k + 0) * H + jw0);
            float4 w1 = *(const float4*)(encW2 + (k + 1) * H + jw0);
            float4 w2 = *(const float4*)(encW2 + (k + 2) * H + jw0);
            float4 w3 = *(const float4*)(encW2 + (k + 3) * H + jw0);
#pragma unroll
            for (int m = 0; m < 8; m++) {
                float4 t = *(const float4*)(bufB + (mb2 + m) * H + k);
                acc[m][0] = fmaf(t.w, w3.x, fmaf(t.z, w2.x, fmaf(t.y, w1.x, fmaf(t.x, w0.x, acc[m][0]))));
                acc[m][1] = fmaf(t.w, w3.y, fmaf(t.z, w2.y, fmaf(t.y, w1.y, fmaf(t.x, w0.y, acc[m][1]))));
                acc[m][2] = fmaf(t.w, w3.z, fmaf(t.z, w2.z, fmaf(t.y, w1.z, fmaf(t.x, w0.z, acc[m][2]))));
                acc[m][3] = fmaf(t.w, w3.w, fmaf(t.z, w2.w, fmaf(t.y, w1.w, fmaf(t.x, w0.w, acc[m][3]))));
            }
        }
        float4 b = *(const float4*)(encB2 + jw0);
#pragma unroll
        for (int m = 0; m < 8; m++) {
            float4 o;
            o.x = fmaxf(acc[m][0] + b.x, 0.f);
            o.y = fmaxf(acc[m][1] + b.y, 0.f);
            o.z = fmaxf(acc[m][2] + b.z, 0.f);
            o.w = fmaxf(acc[m][3] + b.w, 0.f);
            *(float4*)(bufA + (mb2 + m) * H + jw0) = o;
        }
    }
    __syncthreads();
    {
        const int r4 = tid >> 6;
        const int cb = tid & 63;
#pragma unroll
        for (int half = 0; half < 2; half++) {
            const int c = cb + half * 64;
            const float* er = bufA + (r4 * E) * H + c;
            float v[E];
#pragma unroll
            for (int e = 0; e < E; e++) v[e] = er[e * H];
            float s = 0.f;
#pragma unroll
            for (int e = 0; e < E; e++) s += v[e];
            float fc = v[fi];
            float ma = 0.f;
#pragma unroll
            for (int e = 0; e < E; e++) ma += fabsf(v[e] - fc);
            s_full[r4 * H + c] = fc;
            s_glob[r4 * H + c] = s * (1.f / 16.f);
            s_mabs[r4 * H + c] = ma * (1.f / 16.f);
        }
    }
    __syncthreads();
    float* s_pB = bufB;
    float* s_pD = bufB + 2 * R * H;
    {
        const int jp = tid & 63;
        const int jj = jp * 2;
        const int kh = (tid >> 6) & 1;
        const int rg = tid >> 7;
        const int c0 = kh * 64;
        const float* __restrict__ Wb = specW1 + H * H;
        const float* __restrict__ Wc = specW1 + 2 * H * H;
        float accB[2][2] = {{0.f, 0.f}, {0.f, 0.f}};
        float accD[2][2] = {{0.f, 0.f}, {0.f, 0.f}};
        for (int cc = 0; cc < 64; cc++) {
            const int c = c0 + cc;
            float2 wb = *(const float2*)(Wb + c * H + jj);
            float2 wc = *(const float2*)(Wc + c * H + jj);
            float2 d0 = *(const float2*)(defW1 + c * H + jj);
            float2 d1 = *(const float2*)(defW1 + (H + c) * H + jj);
            float2 d2 = *(const float2*)(defW1 + (2 * H + c) * H + jj);
#pragma unroll
            for (int rl = 0; rl < 2; rl++) {
                const int r = rg * 2 + rl;
                float fv = s_full[r * H + c];
                float gv = s_glob[r * H + c];
                float mv = s_mabs[r * H + c];
                accB[rl][0] = fmaf(fv, wb.x, accB[rl][0]);
                accB[rl][1] = fmaf(fv, wb.y, accB[rl][1]);
                accB[rl][0] = fmaf(gv, wc.x, accB[rl][0]);
                accB[rl][1] = fmaf(gv, wc.y, accB[rl][1]);
                accD[rl][0] = fmaf(fv, d0.x, accD[rl][0]);
                accD[rl][1] = fmaf(fv, d0.y, accD[rl][1]);
                accD[rl][0] = fmaf(gv, d1.x, accD[rl][0]);
                accD[rl][1] = fmaf(gv, d1.y, accD[rl][1]);
                accD[rl][0] = fmaf(mv, d2.x, accD[rl][0]);
                accD[rl][1] = fmaf(mv, d2.y, accD[rl][1]);
            }
        }
#pragma unroll
        for (int rl = 0; rl < 2; rl++) {
            const int r = rg * 2 + rl;
            *(float2*)(s_pB + (kh * R + r) * H + jj) = make_float2(accB[rl][0], accB[rl][1]);
            *(float2*)(s_pD + (kh * R + r) * H + jj) = make_float2(accD[rl][0], accD[rl][1]);
        }
    }
    __syncthreads();
    {
        float dv = 0.f;
#pragma unroll
        for (int t = 0; t < 2; t++) {
            const int j = lane + t * 64;
            float pb = s_pB[wq * H + j] + s_pB[(R + wq) * H + j];
            s_bias[wq * H + j] = specB1[j] - pb;
            float pd = defB1[j] + s_pD[wq * H + j] + s_pD[(R + wq) * H + j];
            dv += fmaxf(pd, 0.f) * defW2[j];
        }
#pragma unroll
        for (int off = 32; off; off >>= 1) dv += __shfl_xor(dv, off, 64);
        if (lane == 0) s_dred[wq] = dv;
    }
    __syncthreads();
    {
        float acc[8][4];
#pragma unroll
        for (int m = 0; m < 8; m++)
#pragma unroll
            for (int j = 0; j < 4; j++) acc[m][j] = 0.f;
        const float* __restrict__ Wd = specW1 + 3 * H * H;
        for (int k = 0; k < H; k += 4) {
            float4 wa0, wa1, wa2, wa3;
#pragma unroll
            for (int t = 0; t < 4; t++) {
                const float* p = specW1 + (k + t) * H + jw0;
                float4 x0 = *(const float4*)(p);
                float4 x1 = *(const float4*)(p + H * H);
                float4 x2 = *(const float4*)(p + 2 * H * H);
                float4 s4 = make_float4(x0.x + x1.x + x2.x, x0.y + x1.y + x2.y,
                                        x0.z + x1.z + x2.z, x0.w + x1.w + x2.w);
                if (t == 0) wa0 = s4; else if (t == 1) wa1 = s4;
                else if (t == 2) wa2 = s4; else wa3 = s4;
            }
            float4 wd0 = *(const float4*)(Wd + (k + 0) * H + jw0);
            float4 wd1 = *(const float4*)(Wd + (k + 1) * H + jw0);
            float4 wd2 = *(const float4*)(Wd + (k + 2) * H + jw0);
            float4 wd3 = *(const float4*)(Wd + (k + 3) * H + jw0);
            float4 f4 = *(const float4*)(s_full + wq * H + k);
#pragma unroll
            for (int m = 0; m < 8; m++) {
                float4 ev = *(const float4*)(bufA + (mb2 + m) * H + k);
                float ax = fabsf(ev.x - f4.x);
                float ay = fabsf(ev.y - f4.y);
                float az = fabsf(ev.z - f4.z);
                float aw = fabsf(ev.w - f4.w);
#pragma unroll
                for (int j = 0; j < 4; j++) {
                    const float* waj0 = &wa0.x, *waj1 = &wa1.x, *waj2 = &wa2.x, *waj3 = &wa3.x;
                    const float* wdj0 = &wd0.x, *wdj1 = &wd1.x, *wdj2 = &wd2.x, *wdj3 = &wd3.x;
                    float a = acc[m][j];
                    a = fmaf(ev.x, waj0[j], a);
                    a = fmaf(ev.y, waj1[j], a);
                    a = fmaf(ev.z, waj2[j], a);
                    a = fmaf(ev.w, waj3[j], a);
                    a = fmaf(ax, wdj0[j], a);
                    a = fmaf(ay, wdj1[j], a);
                    a = fmaf(az, wdj2[j], a);
                    a = fmaf(aw, wdj3[j], a);
                    acc[m][j] = a;
                }
            }
        }
        float4 bn = *(const float4*)(s_bias + wq * H + jw0);
        float4 w2 = *(const float4*)(specW2 + jw0);
#pragma unroll
        for (int m = 0; m < 8; m++) {
            float p = 0.f;
            p += fmaxf(acc[m][0] + bn.x, 0.f) * w2.x;
            p += fmaxf(acc[m][1] + bn.y, 0.f) * w2.y;
            p += fmaxf(acc[m][2] + bn.z, 0.f) * w2.z;
            p += fmaxf(acc[m][3] + bn.w, 0.f) * w2.w;
#pragma unroll
            for (int off = 1; off < 32; off <<= 1) p += __shfl_xor(p, off, 64);
            if (jl == 0) s_logits[mb2 + m] = p;
        }
    }
    __syncthreads();
    if (tid < R && (n0 + tid) < N) {
        const int r = tid;
        const int n = n0 + r;
        float s = s_dred[r] + defB2[0];
        out[(size_t)N * E + n] = 1.f / (1.f + expf(-s));
        int k = tkPtr[0];
        if (k < 1) k = 1;
        if (k > E - 1) k = E - 1;
        unsigned chosen = 0u;
        for (int kk = 0; kk < k; kk++) {
            float bv = -INFINITY; int bi = 0;
            for (int e = 0; e < E; e++) {
                if (e == fi || ((chosen >> e) & 1u)) continue;
                float v = s_logits[r * E + e];
                if (v > bv) { bv = v; bi = e; }
            }
            chosen |= (1u << bi);
        }
        float mx = -INFINITY;
        for (int e = 0; e < E; e++)
            if ((chosen >> e) & 1u) { float v = s_logits[r * E + e]; if (v > mx) mx = v; }
        float ssum = 0.f;
        for (int e = 0; e < E; e++)
            if ((chosen >> e) & 1u) ssum += expf(s_logits[r * E + e] - mx);
        float inv = 1.f / ssum;
        for (int e = 0; e < E; e++) {
            float wv = 0.f;
            if ((chosen >> e) & 1u) wv = expf(s_logits[r * E + e] - mx) * inv;
            out[(size_t)n * E + e] = wv;
        }
    }
}

extern "C" void kernel_launch(void* const* d_in, const int* in_sizes, int n_in,
                              void* d_out, int out_size, void* d_ws, size_t ws_size,
                              hipStream_t stream) {
    (void)n_in; (void)out_size;
    const float* tokens = (const float*)d_in[0];
    const float* encW1  = (const float*)d_in[1];
    const float* encB1  = (const float*)d_in[2];
    const float* encW2  = (const float*)d_in[3];
    const float* encB2  = (const float*)d_in[4];
    const float* specW1 = (const float*)d_in[5];
    const float* specB1 = (const float*)d_in[6];
    const float* specW2 = (const float*)d_in[7];
    // d_in[8] = spec_b2 (unused: softmax is shift-invariant)
    const float* defW1  = (const float*)d_in[9];
    const float* defB1  = (const float*)d_in[10];
    const float* defW2  = (const float*)d_in[11];
    const float* defB2  = (const float*)d_in[12];
    const int*   fiPtr  = (const int*)d_in[13];
    const int*   tkPtr  = (const int*)d_in[14];
    float* out = (float*)d_out;

    const int N = in_sizes[0] / (E * D);
    const int grid = (N + R - 1) / R;

    if (d_ws != nullptr && ws_size >= WS_NEED) {
        spec_pack<<<16, 256, 0, stream>>>(specW1, (unsigned short*)d_ws);
        router_mfma<<<grid, 256, 0, stream>>>(
            tokens, encW1, encB1, encW2, encB2, specW1, specB1, specW2,
            defW1, defB1, defW2, defB2, fiPtr, tkPtr,
            (const unsigned short*)d_ws, out, N);
    } else {
        router_fp32<<<grid, 256, 0, stream>>>(
            tokens, encW1, encB1, encW2, encB2, specW1, specB1, specW2,
            defW1, defB1, defW2, defB2, fiPtr, tkPtr, out, N);
    }
}